// Round 10
// baseline (123.814 us; speedup 1.0000x reference)
//
#include <hip/hip_runtime.h>
#include <math.h>

#define BATCH 8
#define CIN   128
#define COUT  128
#define HH    64
#define WW    64
#define OC    27        // 3*K2
#define KDIM  1152      // CIN*9
#define CST   228       // f32 stride per ci in Xf (3*68 + pad headroom)

typedef unsigned short u16;
typedef unsigned int   u32;
typedef __attribute__((ext_vector_type(8))) short bf16x8;
typedef __attribute__((ext_vector_type(4))) float f32x4;

__device__ __forceinline__ float b2f(u16 u) {
    return __uint_as_float((u32)u << 16);
}
__device__ __forceinline__ u16 f2b(float f) {   // RTNE
    u32 u = __float_as_uint(f);
    return (u16)((u + 0x7fffu + ((u >> 16) & 1u)) >> 16);
}
__device__ __forceinline__ float blo(u32 u) { return __uint_as_float(u << 16); }
__device__ __forceinline__ float bhi(u32 u) { return __uint_as_float(u & 0xffff0000u); }
__device__ __forceinline__ u32 cvtpk(float lo, float hi) {
    u32 r;
    asm("v_cvt_pk_bf16_f32 %0, %1, %2" : "=v"(r) : "v"(lo), "v"(hi));
    return r;
}
__device__ __forceinline__ bf16x8 pack8(u32 a, u32 b, u32 c, u32 d) {
    union { u32 u[4]; bf16x8 v; } z;
    z.u[0] = a; z.u[1] = b; z.u[2] = c; z.u[3] = d;
    return z.v;
}

// XCD-ownership swizzle: XCD (o%8) owns image (o%8) end-to-end.
__device__ __forceinline__ int xswiz(int o, int K) { return (o & 7) * K + (o >> 3); }

// ---------------- K_prep: transpose-x(hi only) + pack_w + pack_woff ----------
__global__ __launch_bounds__(256) void k_prep(const float* __restrict__ x,
                                              const float* __restrict__ weight,
                                              const float* __restrict__ w_off,
                                              u16* __restrict__ xtb,
                                              u16* __restrict__ wbf,
                                              u16* __restrict__ wop) {
    __shared__ float tile[64][65];
    int gbid = blockIdx.x;
    int t = threadIdx.x;
    if (gbid < 1024) {
        int bid = xswiz(gbid, 128);
        int b   = bid >> 7;
        int c0  = ((bid >> 6) & 1) << 6;
        int hw0 = (bid & 63) << 6;
        int ln  = t & 63;
        int cq  = t >> 6;
#pragma unroll
        for (int r = 0; r < 16; ++r) {
            int c_l = cq * 16 + r;
            tile[c_l][ln] = x[(((size_t)(b * CIN + c0 + c_l)) << 12) + hw0 + ln];
        }
        __syncthreads();
#pragma unroll
        for (int r = 0; r < 16; ++r) {
            int hw_w = cq * 16 + r;
            xtb[((size_t)(b << 12) + hw0 + hw_w) * 128 + c0 + ln] = f2b(tile[ln][hw_w]);
        }
    } else if (gbid < 1600) {
        int tid = (gbid - 1024) * 256 + t;
        int j  = tid & 7;
        int l  = (tid >> 3) & 63;
        int ni = (tid >> 9) & 7;
        int s  = (tid >> 12) & 3;
        int t9 = tid >> 14;
        int co = ni * 16 + (l & 15);
        int ci = s * 32 + ((l >> 4) << 3) + j;
        wbf[tid] = f2b(weight[co * KDIM + ci * 9 + t9]);
    } else {
        int tid = (gbid - 1600) * 256 + t;
        int j   = tid & 7;
        int l   = (tid >> 3) & 63;
        int ni  = (tid >> 9) & 1;
        int sg  = (tid >> 10) & 3;
        int rest = tid >> 12;
        int t9  = rest % 9;
        int split = rest / 9;
        int co = ni * 16 + (l & 15);
        int ci = sg * 32 + ((l >> 4) << 3) + j;
        float val = (co < OC) ? w_off[co * KDIM + ci * 9 + t9] : 0.f;
        u16 hi = f2b(val);
        u16 lo = f2b(val - b2f(hi));
        wop[tid] = split ? lo : hi;
    }
}

// LDS layout (bytes), total 51632 -> 3 blocks/CU:
//   phase A: Xf   0..29184   (32ci x 228 f32, per ci-round)
//            red  32768..40960
//            omf  44288..51632  (f32 [27 co][68])
//   phase B: Abuf0 0..16384, Abuf1 16384..32768
//            w4   32768..41984 (over dead red)
//            idxp 41984..44288
//            omf persists
__global__ __launch_bounds__(512, 6) void k_fused(const float* __restrict__ x,
                                                  const u16* __restrict__ xtb,
                                                  const u16* __restrict__ wop,
                                                  const u16* __restrict__ wbf,
                                                  const float* __restrict__ b_off,
                                                  const float* __restrict__ bias,
                                                  float* __restrict__ out) {
    __shared__ __align__(16) char smem[51632];
    float* Xf  = (float*)smem;
    float* red = (float*)(smem + 32768);
    float* omf = (float*)(smem + 44288);

    const int t  = threadIdx.x;
    const int lb = xswiz(blockIdx.x, 64);
    const int b  = lb >> 6;
    const int h  = lb & 63;
    const int l    = t & 63;
    const int wv   = t >> 6;
    const int l15  = l & 15;
    const int lg   = l >> 4;

    // ================= PHASE A: offset conv (4 ci-rounds of 32) =================
    {
        const int ntile = wv & 3;       // px tile (16 px)
        const int kgrp  = wv >> 2;      // owns rounds {2*kgrp, 2*kgrp+1}

        // zero px=64..67 pad slots (edge read targets), once
        if (t < 96) {
            int ci = t & 31, row = t >> 5;
            int idx = ci * CST + row * 68 + (((ci >> 3) & 3) << 3) + 64;
            *(float4*)(Xf + idx) = make_float4(0.f, 0.f, 0.f, 0.f);
        }

        f32x4 acc0 = {0.f, 0.f, 0.f, 0.f};   // co 0..15
        f32x4 acc1 = {0.f, 0.f, 0.f, 0.f};   // co 16..31
        float4 st_[3];

        auto stageA_load = [&](int rnd) {
#pragma unroll
            for (int it = 0; it < 3; ++it) {
                int slot = t + it * 512;          // 1536 slots = 96 pairs x 16
                int pair = slot >> 4, ln16 = slot & 15;
                int row = pair >> 5, ci = pair & 31;
                int grow = h - 1 + row;
                float4 v = make_float4(0.f, 0.f, 0.f, 0.f);
                if ((unsigned)grow < 64u)
                    v = *(const float4*)(x + (((size_t)(b * CIN + rnd * 32 + ci)) << 12)
                                           + (grow << 6) + ln16 * 4);
                st_[it] = v;
            }
        };
        auto stageA_store = [&]() {
#pragma unroll
            for (int it = 0; it < 3; ++it) {
                int slot = t + it * 512;
                int pair = slot >> 4, ln16 = slot & 15;
                int row = pair >> 5, ci = pair & 31;
                int idx = ci * CST + row * 68 + (((ci >> 3) & 3) << 3) + ln16 * 4;
                *(float4*)(Xf + idx) = st_[it];
            }
        };
        auto kloopA = [&](int rnd) {
            for (int tap = 0; tap < 9; ++tap) {
                int kh = tap / 3, kw = tap - kh * 3;
                int gw = ntile * 16 + kw - 1 + l15;
                int px = (gw < 0) ? 64 : ((gw > 63) ? 65 : gw);
                int ci0 = lg << 3;
                int base = ci0 * CST + kh * 68 + (lg << 3) + px;
                float f0 = Xf[base], f1 = Xf[base + CST];
                float f2 = Xf[base + 2 * CST], f3 = Xf[base + 3 * CST];
                float f4 = Xf[base + 4 * CST], f5 = Xf[base + 5 * CST];
                float f6 = Xf[base + 6 * CST], f7 = Xf[base + 7 * CST];
                u32 h0 = cvtpk(f0, f1), h1 = cvtpk(f2, f3);
                u32 h2 = cvtpk(f4, f5), h3 = cvtpk(f6, f7);
                u32 l0 = cvtpk(f0 - blo(h0), f1 - bhi(h0));
                u32 l1 = cvtpk(f2 - blo(h1), f3 - bhi(h1));
                u32 l2 = cvtpk(f4 - blo(h2), f5 - bhi(h2));
                u32 l3 = cvtpk(f6 - blo(h3), f7 - bhi(h3));
                bf16x8 ah = pack8(h0, h1, h2, h3);
                bf16x8 al = pack8(l0, l1, l2, l3);
                const u16* B = wop + (((tap * 4 + rnd) * 2) << 9) + (l << 3);
                bf16x8 wh0 = *(const bf16x8*)(B);
                bf16x8 wh1 = *(const bf16x8*)(B + 512);
                bf16x8 wl0 = *(const bf16x8*)(B + 36864);
                bf16x8 wl1 = *(const bf16x8*)(B + 36864 + 512);
                acc0 = __builtin_amdgcn_mfma_f32_16x16x32_bf16(wh0, ah, acc0, 0, 0, 0);
                acc1 = __builtin_amdgcn_mfma_f32_16x16x32_bf16(wh1, ah, acc1, 0, 0, 0);
                acc0 = __builtin_amdgcn_mfma_f32_16x16x32_bf16(wl0, ah, acc0, 0, 0, 0);
                acc1 = __builtin_amdgcn_mfma_f32_16x16x32_bf16(wl1, ah, acc1, 0, 0, 0);
                acc0 = __builtin_amdgcn_mfma_f32_16x16x32_bf16(wh0, al, acc0, 0, 0, 0);
                acc1 = __builtin_amdgcn_mfma_f32_16x16x32_bf16(wh1, al, acc1, 0, 0, 0);
            }
        };

        stageA_load(0);
        stageA_store();
        __syncthreads();
        for (int rnd = 0; rnd < 4; ++rnd) {
            if (rnd < 3) stageA_load(rnd + 1);         // T14: issue early
            if ((rnd >> 1) == kgrp) kloopA(rnd);       // this wave's rounds only
            __syncthreads();
            if (rnd < 3) { stageA_store(); __syncthreads(); }
        }

        // reduce over kgrp, then bias/sigmoid -> om row in LDS (stride 68)
        if (kgrp) {
            float* rp = red + (((ntile << 6) + l) << 3);
            *(f32x4*)rp = acc0;
            *(f32x4*)(rp + 4) = acc1;
        }
        __syncthreads();
        if (!kgrp) {
            const float* rp = red + (((ntile << 6) + l) << 3);
            acc0 += *(const f32x4*)rp;
            acc1 += *(const f32x4*)(rp + 4);
            int px = ntile * 16 + l15;
            int co0 = lg << 2;
#pragma unroll
            for (int r = 0; r < 4; ++r)
                omf[(co0 + r) * 68 + px] = acc0[r] + b_off[co0 + r];
            int co1 = 16 + (lg << 2);
#pragma unroll
            for (int r = 0; r < 4; ++r) {
                int co = co1 + r;
                if (co < OC) {
                    float v = acc1[r] + b_off[co];
                    if (co >= 18) v = 1.f / (1.f + expf(-v));
                    omf[co * 68 + px] = v;
                }
            }
        }
        __syncthreads();
    }

    // ================= PHASE B: bilinear sampling + MFMA GEMM =================
    float (*w4)[4] = (float (*)[4])(smem + 32768);   // 9216 B (over dead red)
    u32* idxp = (u32*)(smem + 41984);                // 2304 B

    for (int i = t; i < 576; i += 512) {
        int p  = i / 9;
        int tt = i - p * 9;
        float dy = omf[tt * 68 + p];
        float dx = omf[(9 + tt) * 68 + p];
        float m  = omf[(18 + tt) * 68 + p];      // sigmoided in phase A
        float py = dy + (float)(h - 1 + tt / 3);
        float px = dx + (float)(p - 1 + tt % 3);
        float y0f = floorf(py), x0f = floorf(px);
        float wy = py - y0f, wx = px - x0f;
        int y0 = (int)y0f, x0 = (int)x0f;
        int y1 = y0 + 1,   x1 = x0 + 1;
        float vy0 = ((unsigned)y0 < 64u) ? 1.f : 0.f;
        float vy1 = ((unsigned)y1 < 64u) ? 1.f : 0.f;
        float vx0 = ((unsigned)x0 < 64u) ? 1.f : 0.f;
        float vx1 = ((unsigned)x1 < 64u) ? 1.f : 0.f;
        w4[i][0] = (1.f - wy) * (1.f - wx) * m * vy0 * vx0;
        w4[i][1] = (1.f - wy) * wx         * m * vy0 * vx1;
        w4[i][2] = wy         * (1.f - wx) * m * vy1 * vx0;
        w4[i][3] = wy         * wx         * m * vy1 * vx1;
        int y0c = min(max(y0, 0), 63);
        int y1c = min(max(y1, 0), 63);
        int x0c = min(max(x0, 0), 63);
        int x1c = min(max(x1, 0), 63);        // CLAMPED x1 — left-edge fix (R9 bug)
        idxp[i] = (u32)y0c | ((u32)y1c << 8) | ((u32)x0c << 16) | ((u32)x1c << 24);
    }
    __syncthreads();

    f32x4 acc[4][2];
#pragma unroll
    for (int pt = 0; pt < 4; ++pt)
#pragma unroll
        for (int nt = 0; nt < 2; ++nt) acc[pt][nt] = (f32x4){0.f, 0.f, 0.f, 0.f};

    const int grp  = t >> 8;        // ci half
    const int tl   = t & 255;
    const int l2   = tl & 63;
    const int wv2  = tl >> 6;       // co group (32 each)
    const int row0 = l2 & 15;
    const int kg   = l2 >> 4;

    const int sp = tl >> 2;         // sampling: pixel 0..63
    const int sc = tl & 3;          // sampling: 16B sub-chunk within 64B
    const u16* xb = xtb + ((size_t)b << 19);

    uint4 g_[2][4];

    auto sample_load = [&](int tt) {
        u32 pk = idxp[sp * 9 + tt];
        int y0 = pk & 255, y1 = (pk >> 8) & 255;
        int x0 = (pk >> 16) & 255, x1 = pk >> 24;
        int d1 = (x1 - x0) << 7;                 // 0 or 128 (clamped step)
        const u16* p0 = xb + (((y0 << 6) | x0) << 7) + grp * 64 + sc * 8;
        const u16* p1 = xb + (((y1 << 6) | x0) << 7) + grp * 64 + sc * 8;
        g_[0][0] = *(const uint4*)(p0);          // (y0,x0)
        g_[0][1] = *(const uint4*)(p0 + d1);     // (y0,x1c)
        g_[0][2] = *(const uint4*)(p1);          // (y1,x0)
        g_[0][3] = *(const uint4*)(p1 + d1);     // (y1,x1c)
        g_[1][0] = *(const uint4*)(p0 + 32);
        g_[1][1] = *(const uint4*)(p0 + d1 + 32);
        g_[1][2] = *(const uint4*)(p1 + 32);
        g_[1][3] = *(const uint4*)(p1 + d1 + 32);
    };

    auto sample_finish = [&](int tt, int buf) {
        int pi = sp * 9 + tt;
        float4 W = *(const float4*)(&w4[pi][0]);
        u16* dst = (u16*)(smem + buf * 16384);
#pragma unroll
        for (int k = 0; k < 2; ++k) {
            uint4 a00 = g_[k][0], a01 = g_[k][1], a10 = g_[k][2], a11 = g_[k][3];
            uint4 ow;
            {
                float e0 = W.x * blo(a00.x) + W.y * blo(a01.x) + W.z * blo(a10.x) + W.w * blo(a11.x);
                float e1 = W.x * bhi(a00.x) + W.y * bhi(a01.x) + W.z * bhi(a10.x) + W.w * bhi(a11.x);
                ow.x = cvtpk(e0, e1);
            }
            {
                float e0 = W.x * blo(a00.y) + W.y * blo(a01.y) + W.z * blo(a10.y) + W.w * blo(a11.y);
                float e1 = W.x * bhi(a00.y) + W.y * bhi(a01.y) + W.z * bhi(a10.y) + W.w * bhi(a11.y);
                ow.y = cvtpk(e0, e1);
            }
            {
                float e0 = W.x * blo(a00.z) + W.y * blo(a01.z) + W.z * blo(a10.z) + W.w * blo(a11.z);
                float e1 = W.x * bhi(a00.z) + W.y * bhi(a01.z) + W.z * bhi(a10.z) + W.w * bhi(a11.z);
                ow.z = cvtpk(e0, e1);
            }
            {
                float e0 = W.x * blo(a00.w) + W.y * blo(a01.w) + W.z * blo(a10.w) + W.w * blo(a11.w);
                float e1 = W.x * bhi(a00.w) + W.y * bhi(a01.w) + W.z * bhi(a10.w) + W.w * bhi(a11.w);
                ow.w = cvtpk(e0, e1);
            }
            int q16 = (grp * 8 + k * 4 + sc) ^ (sp & 15);
            *(uint4*)((char*)dst + (sp << 8) + (q16 << 4)) = ow;
        }
    };

    auto domfma = [&](int t9, int buf) {
        const char* Ab = (const char*)(smem + buf * 16384);
#pragma unroll
        for (int shalf = 0; shalf < 2; ++shalf) {
            int s = grp * 2 + shalf;
            int q = s * 4 + kg;
            int sw = (q ^ row0) << 4;
            bf16x8 a[4];
#pragma unroll
            for (int pt = 0; pt < 4; ++pt)
                a[pt] = *(const bf16x8*)(Ab + ((pt * 16 + row0) << 8) + sw);
            const u16* B = wbf + ((size_t)t9 << 14) + (s << 12) + (wv2 << 10) + (l2 << 3);
            bf16x8 b0 = *(const bf16x8*)(B);
            bf16x8 b1 = *(const bf16x8*)(B + 512);
#pragma unroll
            for (int pt = 0; pt < 4; ++pt) {
                acc[pt][0] = __builtin_amdgcn_mfma_f32_16x16x32_bf16(a[pt], b0, acc[pt][0], 0, 0, 0);
                acc[pt][1] = __builtin_amdgcn_mfma_f32_16x16x32_bf16(a[pt], b1, acc[pt][1], 0, 0, 0);
            }
        }
    };

    sample_load(0);
    sample_finish(0, 0);
    __syncthreads();
    for (int tt = 0; tt < 9; ++tt) {
        if (tt < 8) sample_load(tt + 1);        // issue gathers early
        domfma(tt, tt & 1);                     // MFMA covers gather latency
        if (tt < 8) sample_finish(tt + 1, (tt + 1) & 1);
        __syncthreads();
    }

    // ---- ci-group reduce + epilogue via LDS ----
    float* outs = (float*)smem;                 // 128co x 64px f32 = 32 KB
    if (grp) {
#pragma unroll
        for (int pt = 0; pt < 4; ++pt)
#pragma unroll
            for (int nt = 0; nt < 2; ++nt) {
                int co  = wv2 * 32 + nt * 16 + row0;
                int pxq = pt * 4 + kg;
                *(f32x4*)((char*)outs + (co << 8) + ((pxq ^ (co & 7)) << 4)) = acc[pt][nt];
            }
    }
    __syncthreads();
    if (!grp) {
#pragma unroll
        for (int pt = 0; pt < 4; ++pt)
#pragma unroll
            for (int nt = 0; nt < 2; ++nt) {
                int co  = wv2 * 32 + nt * 16 + row0;
                int pxq = pt * 4 + kg;
                char* ad = (char*)outs + (co << 8) + ((pxq ^ (co & 7)) << 4);
                f32x4 v = *(const f32x4*)ad;
                *(f32x4*)ad = v + acc[pt][nt];
            }
    }
    __syncthreads();
    {
        int co = t >> 2, qt = t & 3;
        float bb = bias[co];
        float* og = out + (((size_t)(b * COUT + co)) << 12) + (h << 6);
#pragma unroll
        for (int j = 0; j < 4; ++j) {
            int pxq = qt * 4 + j;
            f32x4 v = *(const f32x4*)((const char*)outs + (co << 8) + ((pxq ^ (co & 7)) << 4));
            float4 r = make_float4(v.x + bb, v.y + bb, v.z + bb, v.w + bb);
            *reinterpret_cast<float4*>(og + pxq * 4) = r;
        }
    }
}

// ---------------- host ----------------
extern "C" void kernel_launch(void* const* d_in, const int* in_sizes, int n_in,
                              void* d_out, int out_size, void* d_ws, size_t ws_size,
                              hipStream_t stream) {
    const float* x      = (const float*)d_in[0];
    const float* w_off  = (const float*)d_in[1];
    const float* b_off  = (const float*)d_in[2];
    const float* weight = (const float*)d_in[3];
    const float* bias   = (const float*)d_in[4];
    float* out = (float*)d_out;

    u16* xtb = (u16*)d_ws;            // 4194304 u16 (NHWC bf16 hi)
    u16* wbf = xtb + 4194304;         // 147456 u16 (main GEMM B-frags)
    u16* wop = wbf + 147456;          // 73728 u16 (offset frags hi/lo)

    k_prep<<<1888, 256, 0, stream>>>(x, weight, w_off, xtb, wbf, wop);
    k_fused<<<512, 512, 0, stream>>>(x, xtb, wop, wbf, b_off, bias, out);
}

// Round 11
// 53.764 us; speedup vs baseline: 2.3029x; 2.3029x over previous
//
#include <hip/hip_runtime.h>
#include <math.h>

#define BATCH 8
#define CIN   128
#define COUT  128
#define HH    64
#define WW    64
#define OC    27        // 3*K2
#define KDIM  1152      // CIN*9
#define CST   228       // f32 stride per ci in Xf (3*68 + pad headroom)

typedef unsigned short u16;
typedef unsigned int   u32;
typedef __attribute__((ext_vector_type(8))) short bf16x8;
typedef __attribute__((ext_vector_type(4))) float f32x4;

__device__ __forceinline__ float b2f(u16 u) {
    return __uint_as_float((u32)u << 16);
}
__device__ __forceinline__ u16 f2b(float f) {   // RTNE
    u32 u = __float_as_uint(f);
    return (u16)((u + 0x7fffu + ((u >> 16) & 1u)) >> 16);
}
__device__ __forceinline__ float blo(u32 u) { return __uint_as_float(u << 16); }
__device__ __forceinline__ float bhi(u32 u) { return __uint_as_float(u & 0xffff0000u); }
__device__ __forceinline__ u32 cvtpk(float lo, float hi) {
    u32 r;
    asm("v_cvt_pk_bf16_f32 %0, %1, %2" : "=v"(r) : "v"(lo), "v"(hi));
    return r;
}
__device__ __forceinline__ bf16x8 pack8(u32 a, u32 b, u32 c, u32 d) {
    union { u32 u[4]; bf16x8 v; } z;
    z.u[0] = a; z.u[1] = b; z.u[2] = c; z.u[3] = d;
    return z.v;
}

// XCD-ownership swizzle: XCD (o%8) owns image (o%8) end-to-end.
__device__ __forceinline__ int xswiz(int o, int K) { return (o & 7) * K + (o >> 3); }

// ---------------- K_prep: transpose-x(hi only) + pack_w + pack_woff ----------
__global__ __launch_bounds__(256) void k_prep(const float* __restrict__ x,
                                              const float* __restrict__ weight,
                                              const float* __restrict__ w_off,
                                              u16* __restrict__ xtb,
                                              u16* __restrict__ wbf,
                                              u16* __restrict__ wop) {
    __shared__ float tile[64][65];
    int gbid = blockIdx.x;
    int t = threadIdx.x;
    if (gbid < 1024) {
        int bid = xswiz(gbid, 128);
        int b   = bid >> 7;
        int c0  = ((bid >> 6) & 1) << 6;
        int hw0 = (bid & 63) << 6;
        int ln  = t & 63;
        int cq  = t >> 6;
#pragma unroll
        for (int r = 0; r < 16; ++r) {
            int c_l = cq * 16 + r;
            tile[c_l][ln] = x[(((size_t)(b * CIN + c0 + c_l)) << 12) + hw0 + ln];
        }
        __syncthreads();
#pragma unroll
        for (int r = 0; r < 16; ++r) {
            int hw_w = cq * 16 + r;
            xtb[((size_t)(b << 12) + hw0 + hw_w) * 128 + c0 + ln] = f2b(tile[ln][hw_w]);
        }
    } else if (gbid < 1600) {
        int tid = (gbid - 1024) * 256 + t;
        int j  = tid & 7;
        int l  = (tid >> 3) & 63;
        int ni = (tid >> 9) & 7;
        int s  = (tid >> 12) & 3;
        int t9 = tid >> 14;
        int co = ni * 16 + (l & 15);
        int ci = s * 32 + ((l >> 4) << 3) + j;
        wbf[tid] = f2b(weight[co * KDIM + ci * 9 + t9]);
    } else {
        int tid = (gbid - 1600) * 256 + t;
        int j   = tid & 7;
        int l   = (tid >> 3) & 63;
        int ni  = (tid >> 9) & 1;
        int sg  = (tid >> 10) & 3;
        int rest = tid >> 12;
        int t9  = rest % 9;
        int split = rest / 9;
        int co = ni * 16 + (l & 15);
        int ci = sg * 32 + ((l >> 4) << 3) + j;
        float val = (co < OC) ? w_off[co * KDIM + ci * 9 + t9] : 0.f;
        u16 hi = f2b(val);
        u16 lo = f2b(val - b2f(hi));
        wop[tid] = split ? lo : hi;
    }
}

// LDS layout (bytes), total 51632 -> 3 blocks/CU (VGPR must stay ~64: bounds (512,4)):
//   phase A: Xf 0..29184, red 32768..40960, omf 44288..51632
//   phase B: Abuf0 0..16384, Abuf1 16384..32768, w4 32768..41984, idxp 41984..44288
__global__ __launch_bounds__(512, 4) void k_fused(const float* __restrict__ x,
                                                  const u16* __restrict__ xtb,
                                                  const u16* __restrict__ wop,
                                                  const u16* __restrict__ wbf,
                                                  const float* __restrict__ b_off,
                                                  const float* __restrict__ bias,
                                                  float* __restrict__ out) {
    __shared__ __align__(16) char smem[51632];
    float* Xf  = (float*)smem;
    float* red = (float*)(smem + 32768);
    float* omf = (float*)(smem + 44288);

    const int t  = threadIdx.x;
    const int lb = xswiz(blockIdx.x, 64);
    const int b  = lb >> 6;
    const int h  = lb & 63;
    const int l    = t & 63;
    const int wv   = t >> 6;
    const int l15  = l & 15;
    const int lg   = l >> 4;

    // ================= PHASE A: offset conv (4 ci-rounds of 32) =================
    {
        const int ntile = wv & 3;       // px tile (16 px)
        const int kgrp  = wv >> 2;      // owns rounds {2*kgrp, 2*kgrp+1}

        // zero px=64..67 pad slots (edge read targets), once
        if (t < 96) {
            int ci = t & 31, row = t >> 5;
            int idx = ci * CST + row * 68 + (((ci >> 3) & 3) << 3) + 64;
            *(float4*)(Xf + idx) = make_float4(0.f, 0.f, 0.f, 0.f);
        }

        f32x4 acc0 = {0.f, 0.f, 0.f, 0.f};   // co 0..15
        f32x4 acc1 = {0.f, 0.f, 0.f, 0.f};   // co 16..31
        float4 st_[3];

        auto stageA_load = [&](int rnd) {
#pragma unroll
            for (int it = 0; it < 3; ++it) {
                int slot = t + it * 512;          // 1536 slots = 96 pairs x 16
                int pair = slot >> 4, ln16 = slot & 15;
                int row = pair >> 5, ci = pair & 31;
                int grow = h - 1 + row;
                float4 v = make_float4(0.f, 0.f, 0.f, 0.f);
                if ((unsigned)grow < 64u)
                    v = *(const float4*)(x + (((size_t)(b * CIN + rnd * 32 + ci)) << 12)
                                           + (grow << 6) + ln16 * 4);
                st_[it] = v;
            }
        };
        auto stageA_store = [&]() {
#pragma unroll
            for (int it = 0; it < 3; ++it) {
                int slot = t + it * 512;
                int pair = slot >> 4, ln16 = slot & 15;
                int row = pair >> 5, ci = pair & 31;
                int idx = ci * CST + row * 68 + (((ci >> 3) & 3) << 3) + ln16 * 4;
                *(float4*)(Xf + idx) = st_[it];
            }
        };
        auto kloopA = [&](int rnd) {
            for (int tap = 0; tap < 9; ++tap) {
                int kh = tap / 3, kw = tap - kh * 3;
                int gw = ntile * 16 + kw - 1 + l15;
                int px = (gw < 0) ? 64 : ((gw > 63) ? 65 : gw);
                int ci0 = lg << 3;
                int base = ci0 * CST + kh * 68 + (lg << 3) + px;
                float f0 = Xf[base], f1 = Xf[base + CST];
                float f2 = Xf[base + 2 * CST], f3 = Xf[base + 3 * CST];
                float f4 = Xf[base + 4 * CST], f5 = Xf[base + 5 * CST];
                float f6 = Xf[base + 6 * CST], f7 = Xf[base + 7 * CST];
                u32 h0 = cvtpk(f0, f1), h1 = cvtpk(f2, f3);
                u32 h2 = cvtpk(f4, f5), h3 = cvtpk(f6, f7);
                u32 l0 = cvtpk(f0 - blo(h0), f1 - bhi(h0));
                u32 l1 = cvtpk(f2 - blo(h1), f3 - bhi(h1));
                u32 l2 = cvtpk(f4 - blo(h2), f5 - bhi(h2));
                u32 l3 = cvtpk(f6 - blo(h3), f7 - bhi(h3));
                bf16x8 ah = pack8(h0, h1, h2, h3);
                bf16x8 al = pack8(l0, l1, l2, l3);
                const u16* B = wop + (((tap * 4 + rnd) * 2) << 9) + (l << 3);
                bf16x8 wh0 = *(const bf16x8*)(B);
                bf16x8 wh1 = *(const bf16x8*)(B + 512);
                bf16x8 wl0 = *(const bf16x8*)(B + 36864);
                bf16x8 wl1 = *(const bf16x8*)(B + 36864 + 512);
                acc0 = __builtin_amdgcn_mfma_f32_16x16x32_bf16(wh0, ah, acc0, 0, 0, 0);
                acc1 = __builtin_amdgcn_mfma_f32_16x16x32_bf16(wh1, ah, acc1, 0, 0, 0);
                acc0 = __builtin_amdgcn_mfma_f32_16x16x32_bf16(wl0, ah, acc0, 0, 0, 0);
                acc1 = __builtin_amdgcn_mfma_f32_16x16x32_bf16(wl1, ah, acc1, 0, 0, 0);
                acc0 = __builtin_amdgcn_mfma_f32_16x16x32_bf16(wh0, al, acc0, 0, 0, 0);
                acc1 = __builtin_amdgcn_mfma_f32_16x16x32_bf16(wh1, al, acc1, 0, 0, 0);
            }
        };

        stageA_load(0);
        stageA_store();
        __syncthreads();
        for (int rnd = 0; rnd < 4; ++rnd) {
            if (rnd < 3) stageA_load(rnd + 1);         // T14: issue early
            if ((rnd >> 1) == kgrp) kloopA(rnd);       // this wave's rounds only
            __syncthreads();
            if (rnd < 3) { stageA_store(); __syncthreads(); }
        }

        // reduce over kgrp, then bias/sigmoid -> om row in LDS (stride 68)
        if (kgrp) {
            float* rp = red + (((ntile << 6) + l) << 3);
            *(f32x4*)rp = acc0;
            *(f32x4*)(rp + 4) = acc1;
        }
        __syncthreads();
        if (!kgrp) {
            const float* rp = red + (((ntile << 6) + l) << 3);
            acc0 += *(const f32x4*)rp;
            acc1 += *(const f32x4*)(rp + 4);
            int px = ntile * 16 + l15;
            int co0 = lg << 2;
#pragma unroll
            for (int r = 0; r < 4; ++r)
                omf[(co0 + r) * 68 + px] = acc0[r] + b_off[co0 + r];
            int co1 = 16 + (lg << 2);
#pragma unroll
            for (int r = 0; r < 4; ++r) {
                int co = co1 + r;
                if (co < OC) {
                    float v = acc1[r] + b_off[co];
                    if (co >= 18) v = 1.f / (1.f + expf(-v));
                    omf[co * 68 + px] = v;
                }
            }
        }
        __syncthreads();
    }

    // ================= PHASE B: bilinear sampling + MFMA GEMM =================
    float (*w4)[4] = (float (*)[4])(smem + 32768);   // 9216 B (over dead red)
    u32* idxp = (u32*)(smem + 41984);                // 2304 B

    for (int i = t; i < 576; i += 512) {
        int p  = i / 9;
        int tt = i - p * 9;
        float dy = omf[tt * 68 + p];
        float dx = omf[(9 + tt) * 68 + p];
        float m  = omf[(18 + tt) * 68 + p];      // sigmoided in phase A
        float py = dy + (float)(h - 1 + tt / 3);
        float px = dx + (float)(p - 1 + tt % 3);
        float y0f = floorf(py), x0f = floorf(px);
        float wy = py - y0f, wx = px - x0f;
        int y0 = (int)y0f, x0 = (int)x0f;
        int y1 = y0 + 1,   x1 = x0 + 1;
        float vy0 = ((unsigned)y0 < 64u) ? 1.f : 0.f;
        float vy1 = ((unsigned)y1 < 64u) ? 1.f : 0.f;
        float vx0 = ((unsigned)x0 < 64u) ? 1.f : 0.f;
        float vx1 = ((unsigned)x1 < 64u) ? 1.f : 0.f;
        w4[i][0] = (1.f - wy) * (1.f - wx) * m * vy0 * vx0;
        w4[i][1] = (1.f - wy) * wx         * m * vy0 * vx1;
        w4[i][2] = wy         * (1.f - wx) * m * vy1 * vx0;
        w4[i][3] = wy         * wx         * m * vy1 * vx1;
        int y0c = min(max(y0, 0), 63);
        int y1c = min(max(y1, 0), 63);
        int x0c = min(max(x0, 0), 63);
        int x1c = min(max(x1, 0), 63);        // clamped x1 (left-edge fix)
        idxp[i] = (u32)y0c | ((u32)y1c << 8) | ((u32)x0c << 16) | ((u32)x1c << 24);
    }
    __syncthreads();

    f32x4 acc[4][2];
#pragma unroll
    for (int pt = 0; pt < 4; ++pt)
#pragma unroll
        for (int nt = 0; nt < 2; ++nt) acc[pt][nt] = (f32x4){0.f, 0.f, 0.f, 0.f};

    const int grp  = t >> 8;        // ci half
    const int tl   = t & 255;
    const int l2   = tl & 63;
    const int wv2  = tl >> 6;       // co group (32 each)
    const int row0 = l2 & 15;
    const int kg   = l2 >> 4;

    const int sp = tl >> 2;         // sampling: pixel 0..63
    const int sc = tl & 3;          // sampling: 16B sub-chunk within 64B
    const u16* xb = xtb + ((size_t)b << 19);

    uint4 g_[2][4];

    auto sample_load = [&](int tt) {
        u32 pk = idxp[sp * 9 + tt];
        int y0 = pk & 255, y1 = (pk >> 8) & 255;
        int x0 = (pk >> 16) & 255, x1 = pk >> 24;
        int d1 = (x1 - x0) << 7;                 // 0 or 128 (clamped step)
        const u16* p0 = xb + (((y0 << 6) | x0) << 7) + grp * 64 + sc * 8;
        const u16* p1 = xb + (((y1 << 6) | x0) << 7) + grp * 64 + sc * 8;
        g_[0][0] = *(const uint4*)(p0);          // (y0,x0)
        g_[0][1] = *(const uint4*)(p0 + d1);     // (y0,x1c)
        g_[0][2] = *(const uint4*)(p1);          // (y1,x0)
        g_[0][3] = *(const uint4*)(p1 + d1);     // (y1,x1c)
        g_[1][0] = *(const uint4*)(p0 + 32);
        g_[1][1] = *(const uint4*)(p0 + d1 + 32);
        g_[1][2] = *(const uint4*)(p1 + 32);
        g_[1][3] = *(const uint4*)(p1 + d1 + 32);
    };

    auto sample_finish = [&](int tt, int buf) {
        int pi = sp * 9 + tt;
        float4 W = *(const float4*)(&w4[pi][0]);
        u16* dst = (u16*)(smem + buf * 16384);
#pragma unroll
        for (int k = 0; k < 2; ++k) {
            uint4 a00 = g_[k][0], a01 = g_[k][1], a10 = g_[k][2], a11 = g_[k][3];
            uint4 ow;
            {
                float e0 = W.x * blo(a00.x) + W.y * blo(a01.x) + W.z * blo(a10.x) + W.w * blo(a11.x);
                float e1 = W.x * bhi(a00.x) + W.y * bhi(a01.x) + W.z * bhi(a10.x) + W.w * bhi(a11.x);
                ow.x = cvtpk(e0, e1);
            }
            {
                float e0 = W.x * blo(a00.y) + W.y * blo(a01.y) + W.z * blo(a10.y) + W.w * blo(a11.y);
                float e1 = W.x * bhi(a00.y) + W.y * bhi(a01.y) + W.z * bhi(a10.y) + W.w * bhi(a11.y);
                ow.y = cvtpk(e0, e1);
            }
            {
                float e0 = W.x * blo(a00.z) + W.y * blo(a01.z) + W.z * blo(a10.z) + W.w * blo(a11.z);
                float e1 = W.x * bhi(a00.z) + W.y * bhi(a01.z) + W.z * bhi(a10.z) + W.w * bhi(a11.z);
                ow.z = cvtpk(e0, e1);
            }
            {
                float e0 = W.x * blo(a00.w) + W.y * blo(a01.w) + W.z * blo(a10.w) + W.w * blo(a11.w);
                float e1 = W.x * bhi(a00.w) + W.y * bhi(a01.w) + W.z * bhi(a10.w) + W.w * bhi(a11.w);
                ow.w = cvtpk(e0, e1);
            }
            int q16 = (grp * 8 + k * 4 + sc) ^ (sp & 15);
            *(uint4*)((char*)dst + (sp << 8) + (q16 << 4)) = ow;
        }
    };

    auto domfma = [&](int t9, int buf) {
        const char* Ab = (const char*)(smem + buf * 16384);
#pragma unroll
        for (int shalf = 0; shalf < 2; ++shalf) {
            int s = grp * 2 + shalf;
            int q = s * 4 + kg;
            int sw = (q ^ row0) << 4;
            bf16x8 a[4];
#pragma unroll
            for (int pt = 0; pt < 4; ++pt)
                a[pt] = *(const bf16x8*)(Ab + ((pt * 16 + row0) << 8) + sw);
            const u16* B = wbf + ((size_t)t9 << 14) + (s << 12) + (wv2 << 10) + (l2 << 3);
            bf16x8 b0 = *(const bf16x8*)(B);
            bf16x8 b1 = *(const bf16x8*)(B + 512);
#pragma unroll
            for (int pt = 0; pt < 4; ++pt) {
                acc[pt][0] = __builtin_amdgcn_mfma_f32_16x16x32_bf16(a[pt], b0, acc[pt][0], 0, 0, 0);
                acc[pt][1] = __builtin_amdgcn_mfma_f32_16x16x32_bf16(a[pt], b1, acc[pt][1], 0, 0, 0);
            }
        }
    };

    sample_load(0);
    sample_finish(0, 0);
    __syncthreads();
    for (int tt = 0; tt < 9; ++tt) {
        if (tt < 8) sample_load(tt + 1);        // issue gathers early
        domfma(tt, tt & 1);                     // MFMA covers gather latency
        if (tt < 8) sample_finish(tt + 1, (tt + 1) & 1);
        __syncthreads();
    }

    // ---- ci-group reduce + epilogue via LDS ----
    float* outs = (float*)smem;                 // 128co x 64px f32 = 32 KB
    if (grp) {
#pragma unroll
        for (int pt = 0; pt < 4; ++pt)
#pragma unroll
            for (int nt = 0; nt < 2; ++nt) {
                int co  = wv2 * 32 + nt * 16 + row0;
                int pxq = pt * 4 + kg;
                *(f32x4*)((char*)outs + (co << 8) + ((pxq ^ (co & 7)) << 4)) = acc[pt][nt];
            }
    }
    __syncthreads();
    if (!grp) {
#pragma unroll
        for (int pt = 0; pt < 4; ++pt)
#pragma unroll
            for (int nt = 0; nt < 2; ++nt) {
                int co  = wv2 * 32 + nt * 16 + row0;
                int pxq = pt * 4 + kg;
                char* ad = (char*)outs + (co << 8) + ((pxq ^ (co & 7)) << 4);
                f32x4 v = *(const f32x4*)ad;
                *(f32x4*)ad = v + acc[pt][nt];
            }
    }
    __syncthreads();
    {
        int co = t >> 2, qt = t & 3;
        float bb = bias[co];
        float* og = out + (((size_t)(b * COUT + co)) << 12) + (h << 6);
#pragma unroll
        for (int j = 0; j < 4; ++j) {
            int pxq = qt * 4 + j;
            f32x4 v = *(const f32x4*)((const char*)outs + (co << 8) + ((pxq ^ (co & 7)) << 4));
            float4 r = make_float4(v.x + bb, v.y + bb, v.z + bb, v.w + bb);
            *reinterpret_cast<float4*>(og + pxq * 4) = r;
        }
    }
}

// ---------------- host ----------------
extern "C" void kernel_launch(void* const* d_in, const int* in_sizes, int n_in,
                              void* d_out, int out_size, void* d_ws, size_t ws_size,
                              hipStream_t stream) {
    const float* x      = (const float*)d_in[0];
    const float* w_off  = (const float*)d_in[1];
    const float* b_off  = (const float*)d_in[2];
    const float* weight = (const float*)d_in[3];
    const float* bias   = (const float*)d_in[4];
    float* out = (float*)d_out;

    u16* xtb = (u16*)d_ws;            // 4194304 u16 (NHWC bf16 hi)
    u16* wbf = xtb + 4194304;         // 147456 u16 (main GEMM B-frags)
    u16* wop = wbf + 147456;          // 73728 u16 (offset frags hi/lo)

    k_prep<<<1888, 256, 0, stream>>>(x, weight, w_off, xtb, wbf, wop);
    k_fused<<<512, 512, 0, stream>>>(x, xtb, wop, wbf, b_off, bias, out);
}

// Round 12
// 48.186 us; speedup vs baseline: 2.5695x; 1.1158x over previous
//
#include <hip/hip_runtime.h>
#include <math.h>

#define BATCH 8
#define CIN   128
#define COUT  128
#define HH    64
#define WW    64
#define OC    27        // 3*K2
#define KDIM  1152      // CIN*9
#define CST   228       // f32 stride per ci in Xf (3*68 + shift headroom)

typedef unsigned short u16;
typedef unsigned int   u32;
typedef __attribute__((ext_vector_type(8))) short bf16x8;
typedef __attribute__((ext_vector_type(4))) float f32x4;

__device__ __forceinline__ float b2f(u16 u) {
    return __uint_as_float((u32)u << 16);
}
__device__ __forceinline__ u16 f2b(float f) {   // RTNE
    u32 u = __float_as_uint(f);
    return (u16)((u + 0x7fffu + ((u >> 16) & 1u)) >> 16);
}
__device__ __forceinline__ float blo(u32 u) { return __uint_as_float(u << 16); }
__device__ __forceinline__ float bhi(u32 u) { return __uint_as_float(u & 0xffff0000u); }
__device__ __forceinline__ u32 cvtpk(float lo, float hi) {
    u32 r;
    asm("v_cvt_pk_bf16_f32 %0, %1, %2" : "=v"(r) : "v"(lo), "v"(hi));
    return r;
}
__device__ __forceinline__ bf16x8 pack8(u32 a, u32 b, u32 c, u32 d) {
    union { u32 u[4]; bf16x8 v; } z;
    z.u[0] = a; z.u[1] = b; z.u[2] = c; z.u[3] = d;
    return z.v;
}

// XCD-ownership swizzle: XCD (o%8) owns image (o%8) end-to-end.
__device__ __forceinline__ int xswiz(int o, int K) { return (o & 7) * K + (o >> 3); }

// ---------------- K_prep: transpose-x(hi only) + pack_w + pack_woff ----------
__global__ __launch_bounds__(256) void k_prep(const float* __restrict__ x,
                                              const float* __restrict__ weight,
                                              const float* __restrict__ w_off,
                                              u16* __restrict__ xtb,
                                              u16* __restrict__ wbf,
                                              u16* __restrict__ wop) {
    __shared__ float tile[64][65];
    int gbid = blockIdx.x;
    int t = threadIdx.x;
    if (gbid < 1024) {
        int bid = xswiz(gbid, 128);
        int b   = bid >> 7;
        int c0  = ((bid >> 6) & 1) << 6;
        int hw0 = (bid & 63) << 6;
        int ln  = t & 63;
        int cq  = t >> 6;
#pragma unroll
        for (int r = 0; r < 16; ++r) {
            int c_l = cq * 16 + r;
            tile[c_l][ln] = x[(((size_t)(b * CIN + c0 + c_l)) << 12) + hw0 + ln];
        }
        __syncthreads();
#pragma unroll
        for (int r = 0; r < 16; ++r) {
            int hw_w = cq * 16 + r;
            xtb[((size_t)(b << 12) + hw0 + hw_w) * 128 + c0 + ln] = f2b(tile[ln][hw_w]);
        }
    } else if (gbid < 1600) {
        int tid = (gbid - 1024) * 256 + t;
        int j  = tid & 7;
        int l  = (tid >> 3) & 63;
        int ni = (tid >> 9) & 7;
        int s  = (tid >> 12) & 3;
        int t9 = tid >> 14;
        int co = ni * 16 + (l & 15);
        int ci = s * 32 + ((l >> 4) << 3) + j;
        wbf[tid] = f2b(weight[co * KDIM + ci * 9 + t9]);
    } else {
        int tid = (gbid - 1600) * 256 + t;
        int j   = tid & 7;
        int l   = (tid >> 3) & 63;
        int ni  = (tid >> 9) & 1;
        int sg  = (tid >> 10) & 3;
        int rest = tid >> 12;
        int t9  = rest % 9;
        int split = rest / 9;
        int co = ni * 16 + (l & 15);
        int ci = sg * 32 + ((l >> 4) << 3) + j;
        float val = (co < OC) ? w_off[co * KDIM + ci * 9 + t9] : 0.f;
        u16 hi = f2b(val);
        u16 lo = f2b(val - b2f(hi));
        wop[tid] = split ? lo : hi;
    }
}

// LDS (bytes), total 73904 -> 2 blocks/CU (grid-capped at 2 anyway):
//   phase A: Xf 0..58368 (64ci x 228 f32), red 58368..66560, omf 66560..73904 ([27][68] f32)
//   phase B: Abuf0 0..16384, Abuf1 16384..32768, w4 32768..41984, idxp 41984..44288; omf persists
__global__ __launch_bounds__(512, 4) void k_fused(const float* __restrict__ x,
                                                  const u16* __restrict__ xtb,
                                                  const u16* __restrict__ wop,
                                                  const u16* __restrict__ wbf,
                                                  const float* __restrict__ b_off,
                                                  const float* __restrict__ bias,
                                                  float* __restrict__ out) {
    __shared__ __align__(16) char smem[73904];
    float* Xf  = (float*)smem;
    float* red = (float*)(smem + 58368);
    float* omf = (float*)(smem + 66560);

    const int t  = threadIdx.x;
    const int lb = xswiz(blockIdx.x, 64);
    const int b  = lb >> 6;
    const int h  = lb & 63;
    const int l    = t & 63;
    const int wv   = t >> 6;
    const int l15  = l & 15;
    const int lg   = l >> 4;

    // ================= PHASE A: offset conv (R8 structure: 64-ci halves, all waves active) ===
    {
        const int ntile = wv & 3;       // px tile (16 px)
        const int kgrp  = wv >> 2;      // 32-ci chunk within staged half

        // zero the px=64..67 pad slots (edge read targets)
        if (t < 192) {
            int ci = t & 63, row = t >> 6;
            int idx = ci * CST + row * 68 + (((ci >> 3) & 3) << 3) + 64;
            *(float4*)(Xf + idx) = make_float4(0.f, 0.f, 0.f, 0.f);
        }

        f32x4 acc0 = {0.f, 0.f, 0.f, 0.f};   // co 0..15
        f32x4 acc1 = {0.f, 0.f, 0.f, 0.f};   // co 16..31
        float4 st_[6];

        auto stageA_load = [&](int half) {
#pragma unroll
            for (int it = 0; it < 6; ++it) {
                int slot = t + it * 512;          // 3072 slots = 192 pairs x 16
                int pair = slot >> 4, ln16 = slot & 15;
                int row = pair >> 6, ci = pair & 63;
                int grow = h - 1 + row;
                float4 v = make_float4(0.f, 0.f, 0.f, 0.f);
                if ((unsigned)grow < 64u)
                    v = *(const float4*)(x + (((size_t)(b * CIN + half * 64 + ci)) << 12)
                                           + (grow << 6) + ln16 * 4);
                st_[it] = v;
            }
        };
        auto stageA_store = [&]() {
#pragma unroll
            for (int it = 0; it < 6; ++it) {
                int slot = t + it * 512;
                int pair = slot >> 4, ln16 = slot & 15;
                int row = pair >> 6, ci = pair & 63;
                int idx = ci * CST + row * 68 + (((ci >> 3) & 3) << 3) + ln16 * 4;
                *(float4*)(Xf + idx) = st_[it];
            }
        };
        auto kloopA = [&](int half) {
            for (int tap = 0; tap < 9; ++tap) {
                int kh = tap / 3, kw = tap - kh * 3;
                int gw = ntile * 16 + kw - 1 + l15;
                int px = (gw < 0) ? 64 : ((gw > 63) ? 65 : gw);
                int ci0 = kgrp * 32 + (lg << 3);
                int base = ci0 * CST + kh * 68 + (((ci0 >> 3) & 3) << 3) + px;
                float f0 = Xf[base], f1 = Xf[base + CST];
                float f2 = Xf[base + 2 * CST], f3 = Xf[base + 3 * CST];
                float f4 = Xf[base + 4 * CST], f5 = Xf[base + 5 * CST];
                float f6 = Xf[base + 6 * CST], f7 = Xf[base + 7 * CST];
                u32 h0 = cvtpk(f0, f1), h1 = cvtpk(f2, f3);
                u32 h2 = cvtpk(f4, f5), h3 = cvtpk(f6, f7);
                u32 l0 = cvtpk(f0 - blo(h0), f1 - bhi(h0));
                u32 l1 = cvtpk(f2 - blo(h1), f3 - bhi(h1));
                u32 l2 = cvtpk(f4 - blo(h2), f5 - bhi(h2));
                u32 l3 = cvtpk(f6 - blo(h3), f7 - bhi(h3));
                bf16x8 ah = pack8(h0, h1, h2, h3);
                bf16x8 al = pack8(l0, l1, l2, l3);
                int sg = half * 2 + kgrp;
                const u16* B = wop + (((tap * 4 + sg) * 2) << 9) + (l << 3);
                bf16x8 wh0 = *(const bf16x8*)(B);
                bf16x8 wh1 = *(const bf16x8*)(B + 512);
                bf16x8 wl0 = *(const bf16x8*)(B + 36864);
                bf16x8 wl1 = *(const bf16x8*)(B + 36864 + 512);
                __builtin_amdgcn_s_setprio(1);
                acc0 = __builtin_amdgcn_mfma_f32_16x16x32_bf16(wh0, ah, acc0, 0, 0, 0);
                acc1 = __builtin_amdgcn_mfma_f32_16x16x32_bf16(wh1, ah, acc1, 0, 0, 0);
                acc0 = __builtin_amdgcn_mfma_f32_16x16x32_bf16(wl0, ah, acc0, 0, 0, 0);
                acc1 = __builtin_amdgcn_mfma_f32_16x16x32_bf16(wl1, ah, acc1, 0, 0, 0);
                acc0 = __builtin_amdgcn_mfma_f32_16x16x32_bf16(wh0, al, acc0, 0, 0, 0);
                acc1 = __builtin_amdgcn_mfma_f32_16x16x32_bf16(wh1, al, acc1, 0, 0, 0);
                __builtin_amdgcn_s_setprio(0);
            }
        };

        stageA_load(0);
        stageA_store();
        __syncthreads();
        stageA_load(1);          // T14: issue half-1 loads early
        kloopA(0);
        __syncthreads();
        stageA_store();
        __syncthreads();
        kloopA(1);

        // reduce over kgrp, then bias/sigmoid -> om row in LDS (stride 68)
        if (kgrp) {
            float* rp = red + (((ntile << 6) + l) << 3);
            *(f32x4*)rp = acc0;
            *(f32x4*)(rp + 4) = acc1;
        }
        __syncthreads();
        if (!kgrp) {
            const float* rp = red + (((ntile << 6) + l) << 3);
            acc0 += *(const f32x4*)rp;
            acc1 += *(const f32x4*)(rp + 4);
            int px = ntile * 16 + l15;
            int co0 = lg << 2;
#pragma unroll
            for (int r = 0; r < 4; ++r)
                omf[(co0 + r) * 68 + px] = acc0[r] + b_off[co0 + r];
            int co1 = 16 + (lg << 2);
#pragma unroll
            for (int r = 0; r < 4; ++r) {
                int co = co1 + r;
                if (co < OC) {
                    float v = acc1[r] + b_off[co];
                    if (co >= 18) v = 1.f / (1.f + expf(-v));
                    omf[co * 68 + px] = v;
                }
            }
        }
        __syncthreads();
    }

    // ================= PHASE B: bilinear sampling + MFMA GEMM (R11 structure) =================
    float (*w4)[4] = (float (*)[4])(smem + 32768);   // 9216 B (over dead Xf)
    u32* idxp = (u32*)(smem + 41984);                // 2304 B

    for (int i = t; i < 576; i += 512) {
        int p  = i / 9;
        int tt = i - p * 9;
        float dy = omf[tt * 68 + p];
        float dx = omf[(9 + tt) * 68 + p];
        float m  = omf[(18 + tt) * 68 + p];      // sigmoided in phase A
        float py = dy + (float)(h - 1 + tt / 3);
        float px = dx + (float)(p - 1 + tt % 3);
        float y0f = floorf(py), x0f = floorf(px);
        float wy = py - y0f, wx = px - x0f;
        int y0 = (int)y0f, x0 = (int)x0f;
        int y1 = y0 + 1,   x1 = x0 + 1;
        float vy0 = ((unsigned)y0 < 64u) ? 1.f : 0.f;
        float vy1 = ((unsigned)y1 < 64u) ? 1.f : 0.f;
        float vx0 = ((unsigned)x0 < 64u) ? 1.f : 0.f;
        float vx1 = ((unsigned)x1 < 64u) ? 1.f : 0.f;
        w4[i][0] = (1.f - wy) * (1.f - wx) * m * vy0 * vx0;
        w4[i][1] = (1.f - wy) * wx         * m * vy0 * vx1;
        w4[i][2] = wy         * (1.f - wx) * m * vy1 * vx0;
        w4[i][3] = wy         * wx         * m * vy1 * vx1;
        int y0c = min(max(y0, 0), 63);
        int y1c = min(max(y1, 0), 63);
        int x0c = min(max(x0, 0), 63);
        int x1c = min(max(x1, 0), 63);        // clamped x1 (left-edge fix)
        idxp[i] = (u32)y0c | ((u32)y1c << 8) | ((u32)x0c << 16) | ((u32)x1c << 24);
    }
    __syncthreads();

    f32x4 acc[4][2];
#pragma unroll
    for (int pt = 0; pt < 4; ++pt)
#pragma unroll
        for (int nt = 0; nt < 2; ++nt) acc[pt][nt] = (f32x4){0.f, 0.f, 0.f, 0.f};

    const int grp  = t >> 8;        // ci half
    const int tl   = t & 255;
    const int l2   = tl & 63;
    const int wv2  = tl >> 6;       // co group (32 each)
    const int row0 = l2 & 15;
    const int kg   = l2 >> 4;

    const int sp = tl >> 2;         // sampling: pixel 0..63
    const int sc = tl & 3;          // sampling: 16B sub-chunk within 64B
    const u16* xb = xtb + ((size_t)b << 19);

    uint4 g_[2][4];

    auto sample_load = [&](int tt) {
        u32 pk = idxp[sp * 9 + tt];
        int y0 = pk & 255, y1 = (pk >> 8) & 255;
        int x0 = (pk >> 16) & 255, x1 = pk >> 24;
        int d1 = (x1 - x0) << 7;                 // 0 or 128 (clamped step)
        const u16* p0 = xb + (((y0 << 6) | x0) << 7) + grp * 64 + sc * 8;
        const u16* p1 = xb + (((y1 << 6) | x0) << 7) + grp * 64 + sc * 8;
        g_[0][0] = *(const uint4*)(p0);          // (y0,x0)
        g_[0][1] = *(const uint4*)(p0 + d1);     // (y0,x1c)
        g_[0][2] = *(const uint4*)(p1);          // (y1,x0)
        g_[0][3] = *(const uint4*)(p1 + d1);     // (y1,x1c)
        g_[1][0] = *(const uint4*)(p0 + 32);
        g_[1][1] = *(const uint4*)(p0 + d1 + 32);
        g_[1][2] = *(const uint4*)(p1 + 32);
        g_[1][3] = *(const uint4*)(p1 + d1 + 32);
    };

    auto sample_finish = [&](int tt, int buf) {
        int pi = sp * 9 + tt;
        float4 W = *(const float4*)(&w4[pi][0]);
        u16* dst = (u16*)(smem + buf * 16384);
#pragma unroll
        for (int k = 0; k < 2; ++k) {
            uint4 a00 = g_[k][0], a01 = g_[k][1], a10 = g_[k][2], a11 = g_[k][3];
            uint4 ow;
            {
                float e0 = W.x * blo(a00.x) + W.y * blo(a01.x) + W.z * blo(a10.x) + W.w * blo(a11.x);
                float e1 = W.x * bhi(a00.x) + W.y * bhi(a01.x) + W.z * bhi(a10.x) + W.w * bhi(a11.x);
                ow.x = cvtpk(e0, e1);
            }
            {
                float e0 = W.x * blo(a00.y) + W.y * blo(a01.y) + W.z * blo(a10.y) + W.w * blo(a11.y);
                float e1 = W.x * bhi(a00.y) + W.y * bhi(a01.y) + W.z * bhi(a10.y) + W.w * bhi(a11.y);
                ow.y = cvtpk(e0, e1);
            }
            {
                float e0 = W.x * blo(a00.z) + W.y * blo(a01.z) + W.z * blo(a10.z) + W.w * blo(a11.z);
                float e1 = W.x * bhi(a00.z) + W.y * bhi(a01.z) + W.z * bhi(a10.z) + W.w * bhi(a11.z);
                ow.z = cvtpk(e0, e1);
            }
            {
                float e0 = W.x * blo(a00.w) + W.y * blo(a01.w) + W.z * blo(a10.w) + W.w * blo(a11.w);
                float e1 = W.x * bhi(a00.w) + W.y * bhi(a01.w) + W.z * bhi(a10.w) + W.w * bhi(a11.w);
                ow.w = cvtpk(e0, e1);
            }
            int q16 = (grp * 8 + k * 4 + sc) ^ (sp & 15);
            *(uint4*)((char*)dst + (sp << 8) + (q16 << 4)) = ow;
        }
    };

    auto domfma = [&](int t9, int buf) {
        const char* Ab = (const char*)(smem + buf * 16384);
#pragma unroll
        for (int shalf = 0; shalf < 2; ++shalf) {
            int s = grp * 2 + shalf;
            int q = s * 4 + kg;
            int sw = (q ^ row0) << 4;
            bf16x8 a[4];
#pragma unroll
            for (int pt = 0; pt < 4; ++pt)
                a[pt] = *(const bf16x8*)(Ab + ((pt * 16 + row0) << 8) + sw);
            const u16* B = wbf + ((size_t)t9 << 14) + (s << 12) + (wv2 << 10) + (l2 << 3);
            bf16x8 b0 = *(const bf16x8*)(B);
            bf16x8 b1 = *(const bf16x8*)(B + 512);
            __builtin_amdgcn_s_setprio(1);
#pragma unroll
            for (int pt = 0; pt < 4; ++pt) {
                acc[pt][0] = __builtin_amdgcn_mfma_f32_16x16x32_bf16(a[pt], b0, acc[pt][0], 0, 0, 0);
                acc[pt][1] = __builtin_amdgcn_mfma_f32_16x16x32_bf16(a[pt], b1, acc[pt][1], 0, 0, 0);
            }
            __builtin_amdgcn_s_setprio(0);
        }
    };

    sample_load(0);
    sample_finish(0, 0);
    __syncthreads();
    for (int tt = 0; tt < 9; ++tt) {
        if (tt < 8) sample_load(tt + 1);        // issue gathers early
        domfma(tt, tt & 1);                     // MFMA covers gather latency
        if (tt < 8) sample_finish(tt + 1, (tt + 1) & 1);
        __syncthreads();
    }

    // ---- ci-group reduce + epilogue via LDS ----
    float* outs = (float*)smem;                 // 128co x 64px f32 = 32 KB
    if (grp) {
#pragma unroll
        for (int pt = 0; pt < 4; ++pt)
#pragma unroll
            for (int nt = 0; nt < 2; ++nt) {
                int co  = wv2 * 32 + nt * 16 + row0;
                int pxq = pt * 4 + kg;
                *(f32x4*)((char*)outs + (co << 8) + ((pxq ^ (co & 7)) << 4)) = acc[pt][nt];
            }
    }
    __syncthreads();
    if (!grp) {
#pragma unroll
        for (int pt = 0; pt < 4; ++pt)
#pragma unroll
            for (int nt = 0; nt < 2; ++nt) {
                int co  = wv2 * 32 + nt * 16 + row0;
                int pxq = pt * 4 + kg;
                char* ad = (char*)outs + (co << 8) + ((pxq ^ (co & 7)) << 4);
                f32x4 v = *(const f32x4*)ad;
                *(f32x4*)ad = v + acc[pt][nt];
            }
    }
    __syncthreads();
    {
        int co = t >> 2, qt = t & 3;
        float bb = bias[co];
        float* og = out + (((size_t)(b * COUT + co)) << 12) + (h << 6);
#pragma unroll
        for (int j = 0; j < 4; ++j) {
            int pxq = qt * 4 + j;
            f32x4 v = *(const f32x4*)((const char*)outs + (co << 8) + ((pxq ^ (co & 7)) << 4));
            float4 r = make_float4(v.x + bb, v.y + bb, v.z + bb, v.w + bb);
            *reinterpret_cast<float4*>(og + pxq * 4) = r;
        }
    }
}

// ---------------- host ----------------
extern "C" void kernel_launch(void* const* d_in, const int* in_sizes, int n_in,
                              void* d_out, int out_size, void* d_ws, size_t ws_size,
                              hipStream_t stream) {
    const float* x      = (const float*)d_in[0];
    const float* w_off  = (const float*)d_in[1];
    const float* b_off  = (const float*)d_in[2];
    const float* weight = (const float*)d_in[3];
    const float* bias   = (const float*)d_in[4];
    float* out = (float*)d_out;

    u16* xtb = (u16*)d_ws;            // 4194304 u16 (NHWC bf16 hi)
    u16* wbf = xtb + 4194304;         // 147456 u16 (main GEMM B-frags)
    u16* wop = wbf + 147456;          // 73728 u16 (offset frags hi/lo)

    k_prep<<<1888, 256, 0, stream>>>(x, weight, w_off, xtb, wbf, wop);
    k_fused<<<512, 512, 0, stream>>>(x, xtb, wop, wbf, b_off, bias, out);
}